// Round 9
// baseline (275.320 us; speedup 1.0000x reference)
//
#include <hip/hip_runtime.h>

#define NB 4096
#define DK 1024
#define EPSF 1e-6f
#define QS 32.0f          // fp4 pre-scale 2^5: normalized entries sigma=1/32 -> sigma=1

typedef __attribute__((ext_vector_type(8))) int   i32x8_t;
typedef __attribute__((ext_vector_type(4))) int   i32x4_t;
typedef __attribute__((ext_vector_type(4))) float f32x4_t;

#if defined(__has_builtin)
#if __has_builtin(__builtin_amdgcn_cvt_scalef32_pk_fp4_f32)
#define HW_FP4 1
#endif
#endif

// ---------------------------------------------------------------------------
// Global fp4 layout (r0 swizzle): row,k -> p=row>>4, r=row&15, kb=k>>7,
// slot s=(k>>5)&3:  byte = p*8192 + kb*1024 + r*64 + ((s^(r&3))<<4) + ((k&31)>>1)
// (p,kb) chunk = 1 KB contiguous -> one 64-lane x 16 B DMA (linear LDS dest,
// pre-swizzled source; fragment read applies the same XOR -> rule #21 ok).
// ---------------------------------------------------------------------------

__device__ __forceinline__ void async16(const void* g, void* lds) {
    __builtin_amdgcn_global_load_lds(
        (const __attribute__((address_space(1))) void*)g,
        (__attribute__((address_space(3))) void*)lds, 16, 0, 0);
}

// branchless e2m1 encode fallback: grid 0,.5,1,1.5,2,3,4,6.
__device__ __forceinline__ unsigned enc4(float v) {
    const float a = fabsf(v);
    unsigned c = (a >= 0.25f) + (a >= 0.75f) + (a >= 1.25f) + (a >= 1.75f)
               + (a >= 2.5f)  + (a >= 3.5f)  + (a >= 5.0f);
    return c | ((v < 0.f) ? 8u : 0u);
}

// ---------------------------------------------------------------------------
// Kernel 1: wave-per-row normalize -> fp4 e2m1 swizzled; exact fp32 diagonal;
// zeroes rowsum/colsum (atomic targets) + gemm done-counter.
// ---------------------------------------------------------------------------
__global__ __launch_bounds__(256) void normalize_rows(
    const float* __restrict__ x, const float* __restrict__ y,
    unsigned char* __restrict__ xq, unsigned char* __restrict__ yq,
    float* __restrict__ sdiag, float* __restrict__ zerobuf,
    unsigned* __restrict__ donecnt)
{
    const int t = threadIdx.x;
    const int gid = blockIdx.x * 256 + t;
    if (gid < 2 * NB) zerobuf[gid] = 0.f;   // rowsum+colsum contiguous
    if (gid == 0) *donecnt = 0u;

    const int wave = t >> 6;
    const int lane = t & 63;
    const int row  = blockIdx.x * 4 + wave;

    const float4* xr = reinterpret_cast<const float4*>(x + (size_t)row * DK);
    const float4* yr = reinterpret_cast<const float4*>(y + (size_t)row * DK);

    float4 xv[4], yv[4];
    float ssx = 0.f, ssy = 0.f, sxy = 0.f;
    #pragma unroll
    for (int jj = 0; jj < 4; ++jj) {
        xv[jj] = xr[lane * 4 + jj];
        yv[jj] = yr[lane * 4 + jj];
        ssx += xv[jj].x*xv[jj].x + xv[jj].y*xv[jj].y + xv[jj].z*xv[jj].z + xv[jj].w*xv[jj].w;
        ssy += yv[jj].x*yv[jj].x + yv[jj].y*yv[jj].y + yv[jj].z*yv[jj].z + yv[jj].w*yv[jj].w;
        sxy += xv[jj].x*yv[jj].x + xv[jj].y*yv[jj].y + xv[jj].z*yv[jj].z + xv[jj].w*yv[jj].w;
    }
    #pragma unroll
    for (int off = 1; off < 64; off <<= 1) {
        ssx += __shfl_xor(ssx, off, 64);
        ssy += __shfl_xor(ssy, off, 64);
        sxy += __shfl_xor(sxy, off, 64);
    }
    const float invx = 1.0f / fmaxf(sqrtf(ssx), EPSF);
    const float invy = 1.0f / fmaxf(sqrtf(ssy), EPSF);
    const float sx = invx * QS;
    const float sy = invy * QS;

    float fx[16], fy[16];
    #pragma unroll
    for (int jj = 0; jj < 4; ++jj) {
        fx[jj*4+0] = xv[jj].x; fx[jj*4+1] = xv[jj].y;
        fx[jj*4+2] = xv[jj].z; fx[jj*4+3] = xv[jj].w;
        fy[jj*4+0] = yv[jj].x; fy[jj*4+1] = yv[jj].y;
        fy[jj*4+2] = yv[jj].z; fy[jj*4+3] = yv[jj].w;
    }

    unsigned xb0, xb1, yb0, yb1;
#ifdef HW_FP4
    // byte m = {fp4(f[2m+1])<<4 | fp4(f[2m])}: pk convention src0 -> low nibble.
    #define CVT8(dst, f, s)                                                        \
        dst = __builtin_amdgcn_cvt_scalef32_pk_fp4_f32(0u,  (f)[0]*(s), (f)[1]*(s), 1.0f, 0); \
        dst = __builtin_amdgcn_cvt_scalef32_pk_fp4_f32(dst, (f)[2]*(s), (f)[3]*(s), 1.0f, 1); \
        dst = __builtin_amdgcn_cvt_scalef32_pk_fp4_f32(dst, (f)[4]*(s), (f)[5]*(s), 1.0f, 2); \
        dst = __builtin_amdgcn_cvt_scalef32_pk_fp4_f32(dst, (f)[6]*(s), (f)[7]*(s), 1.0f, 3)
    CVT8(xb0, fx,     sx);
    CVT8(xb1, fx + 8, sx);
    CVT8(yb0, fy,     sy);
    CVT8(yb1, fy + 8, sy);
    #undef CVT8
#else
    unsigned xb[2] = {0u, 0u}, yb[2] = {0u, 0u};
    #pragma unroll
    for (int j = 0; j < 16; ++j) {
        xb[j >> 3] |= enc4(fx[j] * sx) << ((j & 7) * 4);
        yb[j >> 3] |= enc4(fy[j] * sy) << ((j & 7) * 4);
    }
    xb0 = xb[0]; xb1 = xb[1]; yb0 = yb[0]; yb1 = yb[1];
#endif

    const int p = row >> 4, r = row & 15;
    const unsigned off = (unsigned)p * 8192 + (lane >> 3) * 1024 + r * 64
                       + ((((lane & 7) >> 1) ^ (r & 3)) << 4) + (lane & 1) * 8;
    *reinterpret_cast<uint2*>(xq + off) = make_uint2(xb0, xb1);
    *reinterpret_cast<uint2*>(yq + off) = make_uint2(yb0, yb1);

    if (lane == 0) sdiag[row] = sxy * invx * invy;
}

// ---------------------------------------------------------------------------
// Kernel 2 (r9): whole-K-in-LDS + 2 blocks/CU overlap + fused finalize.
//   64x64 tile: A 32 KB + B 32 KB = 64 KB LDS -> 2 blocks/CU. grid 4096
//   (XCD-bijective, 8 rounds of 512). Per block: stage ALL 8 K-chunks once
//   (16 DMAs/wave), ONE vmcnt(0) + ONE barrier total, then 32 ds_read +
//   32 MFMA straight-line (zero mid-loop barriers -- the r1-r7 per-step
//   drain is gone); the co-resident block hides the stage latency (r8's
//   1-block/CU flaw fixed). Epilogue: r6 atomics (exonerated by r7).
//   Finalize fused as last-block epilogue (saves the ~10-18us separate
//   kernel; r5-vs-r6 subtraction).
// ---------------------------------------------------------------------------
__global__ __launch_bounds__(256, 2) void gemm_exp_sums(
    const unsigned char* __restrict__ xq, const unsigned char* __restrict__ yq,
    float* __restrict__ rowsum, float* __restrict__ colsum,
    const float* __restrict__ sdiag, unsigned* __restrict__ donecnt,
    float* __restrict__ out)
{
    __shared__ __align__(16) unsigned char LDS[65536];   // A: 0-32K, B: 32K-64K
    __shared__ unsigned lastFlag;
    __shared__ double dred[4];

    const int t    = threadIdx.x;
    const int lane = t & 63;
    const int wave = t >> 6;        // 0..3
    const int q    = lane >> 4;
    const int l15  = lane & 15;

    // XCD swizzle: 8 XCDs x 512 consecutive tiles each (bijective, 4096%8==0)
    const int bid = blockIdx.x;
    const int swz = (bid & 7) * 512 + (bid >> 3);
    const int by  = swz >> 6;       // 0..63 row-tile
    const int bx  = swz & 63;       // 0..63 col-tile

    const int R0 = by * 64;
    const int C0 = bx * 64;
    const int wRow = (wave >> 1) * 32;   // 0 or 32
    const int wCol = (wave & 1) * 32;    // 0 or 32

    f32x4_t acc[2][2];
    #pragma unroll
    for (int i = 0; i < 2; i++)
        #pragma unroll
        for (int j = 0; j < 2; j++)
            acc[i][j] = (f32x4_t){0.f, 0.f, 0.f, 0.f};

    // ---- one-shot stage: wave w loads panel w of A and of B, all 8 kb.
    // LDS chunk (panelLocal p, kb) at (p*8+kb)*1024 (A), +32K (B).
    {
        const unsigned char* srcA =
            xq + (size_t)((R0 >> 4) + wave) * 8192 + lane * 16;
        const unsigned char* srcB =
            yq + (size_t)((C0 >> 4) + wave) * 8192 + lane * 16;
        #pragma unroll
        for (int kb = 0; kb < 8; ++kb) {
            async16(srcA + kb * 1024, &LDS[(wave * 8 + kb) * 1024]);
            async16(srcB + kb * 1024, &LDS[32768 + (wave * 8 + kb) * 1024]);
        }
    }
    __builtin_amdgcn_s_waitcnt(0xF70);   // vmcnt(0): this wave's 16 DMAs done
    __syncthreads();                     // tile resident; LDS read-only now

    const int sl = (q ^ (l15 & 3)) << 4;   // swizzled 16-B slot within row

    // ---- pure ds_read + MFMA; no barriers, no waitcnts; compiler schedules.
    #pragma unroll
    for (int kb = 0; kb < 8; ++kb) {
        i32x8_t bfr[2];
        #pragma unroll
        for (int nt = 0; nt < 2; ++nt) {
            const i32x4_t v = *reinterpret_cast<const i32x4_t*>(
                &LDS[32768 + (((wCol >> 4) + nt) * 8 + kb) * 1024 + l15 * 64 + sl]);
            bfr[nt][0] = v[0]; bfr[nt][1] = v[1]; bfr[nt][2] = v[2]; bfr[nt][3] = v[3];
            bfr[nt][4] = 0;    bfr[nt][5] = 0;    bfr[nt][6] = 0;    bfr[nt][7] = 0;
        }
        #pragma unroll
        for (int mt = 0; mt < 2; ++mt) {
            const i32x4_t v = *reinterpret_cast<const i32x4_t*>(
                &LDS[(((wRow >> 4) + mt) * 8 + kb) * 1024 + l15 * 64 + sl]);
            i32x8_t af;
            af[0] = v[0]; af[1] = v[1]; af[2] = v[2]; af[3] = v[3];
            af[4] = 0;    af[5] = 0;    af[6] = 0;    af[7] = 0;
            #pragma unroll
            for (int nt = 0; nt < 2; ++nt)
                acc[mt][nt] = __builtin_amdgcn_mfma_scale_f32_16x16x128_f8f6f4(
                    af, bfr[nt], acc[mt][nt],
                    4, 4,                       // cbsz=fp4(e2m1), blgp=fp4(e2m1)
                    0, 0x7F7F7F7F,              // A scales: E8M0 127 = 2^0
                    0, 0x7F7F7F7F);             // B scales: 2^0
        }
    }

    // Epilogue (r6-exact): E = exp2(acc/(1024*TAU*ln2)); atomic row/col sums.
    const float kScale = (float)(1.0 / (1024.0 * 0.07 * 0.6931471805599453));
    float csum[2] = {0.f, 0.f};
    #pragma unroll
    for (int mt = 0; mt < 2; ++mt) {
        float rsum[4] = {0.f, 0.f, 0.f, 0.f};
        #pragma unroll
        for (int nt = 0; nt < 2; ++nt) {
            #pragma unroll
            for (int r = 0; r < 4; ++r) {
                const float e = exp2f(acc[mt][nt][r] * kScale);
                rsum[r]  += e;
                csum[nt] += e;
            }
        }
        #pragma unroll
        for (int r = 0; r < 4; ++r) {
            float v = rsum[r];
            v += __shfl_xor(v, 1, 64);
            v += __shfl_xor(v, 2, 64);
            v += __shfl_xor(v, 4, 64);
            v += __shfl_xor(v, 8, 64);
            if (l15 == 0)
                atomicAdd(&rowsum[R0 + wRow + mt * 16 + q * 4 + r], v);
        }
    }
    #pragma unroll
    for (int nt = 0; nt < 2; ++nt) {
        float v = csum[nt];
        v += __shfl_xor(v, 16, 64);
        v += __shfl_xor(v, 32, 64);
        if (lane < 16)
            atomicAdd(&colsum[C0 + wCol + nt * 16 + l15], v);
    }

    // ---- fused finalize: last of 4096 blocks computes the scalar loss ----
    __syncthreads();
    if (t == 0) {
        __threadfence();
        const unsigned old = __hip_atomic_fetch_add(
            donecnt, 1u, __ATOMIC_ACQ_REL, __HIP_MEMORY_SCOPE_AGENT);
        lastFlag = (old == 4095u) ? 1u : 0u;
    }
    __syncthreads();
    if (lastFlag) {
        const float extra = (float)(NB * 1e-6 + 1e-6);
        double local = 0.0;
        for (int i = t; i < NB; i += 256) {
            const float rs = __hip_atomic_load(&rowsum[i], __ATOMIC_RELAXED,
                                               __HIP_MEMORY_SCOPE_AGENT);
            const float cs = __hip_atomic_load(&colsum[i], __ATOMIC_RELAXED,
                                               __HIP_MEMORY_SCOPE_AGENT);
            local += (double)sdiag[i] * (2.0 / 0.07)
                   - (double)logf(rs + extra)
                   - (double)logf(cs + extra);
        }
        #pragma unroll
        for (int off = 1; off < 64; off <<= 1)
            local += __shfl_xor(local, off, 64);
        if ((t & 63) == 0) dred[t >> 6] = local;
        __syncthreads();
        if (t == 0) {
            double tot = dred[0] + dred[1] + dred[2] + dred[3];
            out[0] = (float)(tot * (-1.0 / (2.0 * NB)));
        }
    }
}

// ---------------------------------------------------------------------------
extern "C" void kernel_launch(void* const* d_in, const int* in_sizes, int n_in,
                              void* d_out, int out_size, void* d_ws, size_t ws_size,
                              hipStream_t stream)
{
    const float* x = (const float*)d_in[0];
    const float* y = (const float*)d_in[1];
    float* out = (float*)d_out;

    char* ws = (char*)d_ws;
    unsigned char* xq = (unsigned char*)ws;                                 // 2 MB fp4 swizzled
    unsigned char* yq = (unsigned char*)(ws + (size_t)2 * 1024 * 1024);     // 2 MB fp4 swizzled
    float* rowsum = (float*)(ws + (size_t)8 * 1024 * 1024);                 // 16 KB
    float* colsum = rowsum + NB;                                            // 16 KB
    float* sdiag  = colsum + NB;                                            // 16 KB
    unsigned* donecnt = (unsigned*)(sdiag + NB);                            // 4 B

    normalize_rows<<<NB / 4, 256, 0, stream>>>(x, y, xq, yq, sdiag,
                                               rowsum, donecnt);

    gemm_exp_sums<<<4096, 256, 0, stream>>>(xq, yq, rowsum, colsum,
                                            sdiag, donecnt, out);
}

// Round 10
// 108.313 us; speedup vs baseline: 2.5419x; 2.5419x over previous
//
#include <hip/hip_runtime.h>

#define NB 4096
#define DK 1024
#define EPSF 1e-6f
#define QS 32.0f          // fp4 pre-scale 2^5: normalized entries sigma=1/32 -> sigma=1

typedef __attribute__((ext_vector_type(8)))  int   i32x8_t;
typedef __attribute__((ext_vector_type(4)))  int   i32x4_t;
typedef __attribute__((ext_vector_type(16))) float f32x16_t;

#if defined(__has_builtin)
#if __has_builtin(__builtin_amdgcn_cvt_scalef32_pk_fp4_f32)
#define HW_FP4 1
#endif
#endif

// ---------------------------------------------------------------------------
// Global fp4 layout (r5 swizzle incl. panel parity): row,k -> p=row>>4,
// r=row&15, kb=k>>7, slot s=(k>>5)&3:
//   byte = p*8192 + kb*1024 + r*64 + ((s ^ (r&3) ^ (p&1))<<4) + ((k&31)>>1)
// (p,kb) chunk = 1 KB contiguous -> one 64-lane x 16 B DMA (linear LDS dest,
// pre-swizzled source; fragment read applies the same XOR -> rule #21 ok).
// Panel-parity XOR keeps the 32-row fragment read at 4-way bank degree.
// ---------------------------------------------------------------------------

__device__ __forceinline__ void async16(const void* g, void* lds) {
    __builtin_amdgcn_global_load_lds(
        (const __attribute__((address_space(1))) void*)g,
        (__attribute__((address_space(3))) void*)lds, 16, 0, 0);
}

// branchless e2m1 encode fallback: grid 0,.5,1,1.5,2,3,4,6.
__device__ __forceinline__ unsigned enc4(float v) {
    const float a = fabsf(v);
    unsigned c = (a >= 0.25f) + (a >= 0.75f) + (a >= 1.25f) + (a >= 1.75f)
               + (a >= 2.5f)  + (a >= 3.5f)  + (a >= 5.0f);
    return c | ((v < 0.f) ? 8u : 0u);
}

// ---------------------------------------------------------------------------
// Kernel 1 (r5-exact): wave-per-row normalize -> fp4 e2m1 (x32), panel-parity
// swizzled layout; exact fp32 diagonal; zeroes rowsum/colsum/accum/donecnt.
// ---------------------------------------------------------------------------
__global__ __launch_bounds__(256) void normalize_rows(
    const float* __restrict__ x, const float* __restrict__ y,
    unsigned char* __restrict__ xq, unsigned char* __restrict__ yq,
    float* __restrict__ sdiag, float* __restrict__ zerobuf,
    double* __restrict__ accum, unsigned* __restrict__ donecnt)
{
    const int t = threadIdx.x;
    const int gid = blockIdx.x * 256 + t;
    if (gid < 2 * NB) zerobuf[gid] = 0.f;                 // rowsum+colsum
    if (gid == 0) { *accum = 0.0; *donecnt = 0u; }        // finalize scratch

    const int wave = t >> 6;
    const int lane = t & 63;
    const int row  = blockIdx.x * 4 + wave;

    const float4* xr = reinterpret_cast<const float4*>(x + (size_t)row * DK);
    const float4* yr = reinterpret_cast<const float4*>(y + (size_t)row * DK);

    float4 xv[4], yv[4];
    float ssx = 0.f, ssy = 0.f, sxy = 0.f;
    #pragma unroll
    for (int jj = 0; jj < 4; ++jj) {
        xv[jj] = xr[lane * 4 + jj];
        yv[jj] = yr[lane * 4 + jj];
        ssx += xv[jj].x*xv[jj].x + xv[jj].y*xv[jj].y + xv[jj].z*xv[jj].z + xv[jj].w*xv[jj].w;
        ssy += yv[jj].x*yv[jj].x + yv[jj].y*yv[jj].y + yv[jj].z*yv[jj].z + yv[jj].w*yv[jj].w;
        sxy += xv[jj].x*yv[jj].x + xv[jj].y*yv[jj].y + xv[jj].z*yv[jj].z + xv[jj].w*yv[jj].w;
    }
    #pragma unroll
    for (int off = 1; off < 64; off <<= 1) {
        ssx += __shfl_xor(ssx, off, 64);
        ssy += __shfl_xor(ssy, off, 64);
        sxy += __shfl_xor(sxy, off, 64);
    }
    const float invx = 1.0f / fmaxf(sqrtf(ssx), EPSF);
    const float invy = 1.0f / fmaxf(sqrtf(ssy), EPSF);
    const float sx = invx * QS;
    const float sy = invy * QS;

    float fx[16], fy[16];
    #pragma unroll
    for (int jj = 0; jj < 4; ++jj) {
        fx[jj*4+0] = xv[jj].x; fx[jj*4+1] = xv[jj].y;
        fx[jj*4+2] = xv[jj].z; fx[jj*4+3] = xv[jj].w;
        fy[jj*4+0] = yv[jj].x; fy[jj*4+1] = yv[jj].y;
        fy[jj*4+2] = yv[jj].z; fy[jj*4+3] = yv[jj].w;
    }

    unsigned xb0, xb1, yb0, yb1;
#ifdef HW_FP4
    // byte m = {fp4(f[2m+1])<<4 | fp4(f[2m])}: pk convention src0 -> low nibble.
    #define CVT8(dst, f, s)                                                        \
        dst = __builtin_amdgcn_cvt_scalef32_pk_fp4_f32(0u,  (f)[0]*(s), (f)[1]*(s), 1.0f, 0); \
        dst = __builtin_amdgcn_cvt_scalef32_pk_fp4_f32(dst, (f)[2]*(s), (f)[3]*(s), 1.0f, 1); \
        dst = __builtin_amdgcn_cvt_scalef32_pk_fp4_f32(dst, (f)[4]*(s), (f)[5]*(s), 1.0f, 2); \
        dst = __builtin_amdgcn_cvt_scalef32_pk_fp4_f32(dst, (f)[6]*(s), (f)[7]*(s), 1.0f, 3)
    CVT8(xb0, fx,     sx);
    CVT8(xb1, fx + 8, sx);
    CVT8(yb0, fy,     sy);
    CVT8(yb1, fy + 8, sy);
    #undef CVT8
#else
    unsigned xb[2] = {0u, 0u}, yb[2] = {0u, 0u};
    #pragma unroll
    for (int j = 0; j < 16; ++j) {
        xb[j >> 3] |= enc4(fx[j] * sx) << ((j & 7) * 4);
        yb[j >> 3] |= enc4(fy[j] * sy) << ((j & 7) * 4);
    }
    xb0 = xb[0]; xb1 = xb[1]; yb0 = yb[0]; yb1 = yb[1];
#endif

    const int p = row >> 4, r = row & 15;
    const unsigned off = (unsigned)p * 8192 + (lane >> 3) * 1024 + r * 64
                       + ((((lane & 7) >> 1) ^ (r & 3) ^ (p & 1)) << 4) + (lane & 1) * 8;
    *reinterpret_cast<uint2*>(xq + off) = make_uint2(xb0, xb1);
    *reinterpret_cast<uint2*>(yq + off) = make_uint2(yb0, yb1);

    if (lane == 0) sdiag[row] = sxy * invx * invy;
}

// ---------------------------------------------------------------------------
// Kernel 2 (r10 = r5 gemm SANS fused finalize): m97 structure, 128x128 tile,
// 4 waves, 4 blocks/CU, dbuf global_load_lds, one drain+barrier per K-step,
// v_mfma_f32_32x32x64_f8f6f4 core (wave 64x64 = 2x2 32x32 accs).
// r9 post-mortem: the fused finalize's single-line ACQ_REL done-counter is an
// inter-XCD convoy at ~45ns/block (r9: 4096 blocks = +180us); subtracting it,
// THIS gemm body was the session's fastest (~23us in r5). Fusion removed.
//   A/B frag: row=lane&31, k-block=lane>>5; C/D: col=lane&31,
//   row=(reg&3)+8*(reg>>2)+4*(lane>>5)  [m101, verified passing in r5].
// ---------------------------------------------------------------------------
__global__ __launch_bounds__(256, 4) void gemm_exp_sums(
    const unsigned char* __restrict__ xq, const unsigned char* __restrict__ yq,
    float* __restrict__ rowsum, float* __restrict__ colsum)
{
    __shared__ __align__(16) unsigned char LDS[2][16384];  // [buf][A:0-8K | B:8K-16K]

    const int t    = threadIdx.x;
    const int lane = t & 63;
    const int wave = t >> 6;        // 0..3
    const int r32  = lane & 31;     // fragment row / col
    const int h    = lane >> 5;     // k half-block selector
    const int rp   = r32 & 15;      // within-panel row
    const int pa   = r32 >> 4;      // panel parity within 32-row fragment

    const int R0 = blockIdx.y * 128;
    const int C0 = blockIdx.x * 128;
    const int wRow = (wave >> 1) * 64;   // 0 or 64
    const int wCol = (wave & 1) * 64;    // 0 or 64

    f32x16_t acc[2][2];
    #pragma unroll
    for (int i = 0; i < 2; i++)
        #pragma unroll
        for (int j = 0; j < 2; j++)
            acc[i][j] = (f32x16_t)(0.f);

    // wave w stages A panels {2w,2w+1} and B panels {2w,2w+1}: 4 DMAs/lane/stage
    const unsigned char* srcA =
        xq + (size_t)((R0 >> 4) + 2 * wave) * 8192 + lane * 16;
    const unsigned char* srcB =
        yq + (size_t)((C0 >> 4) + 2 * wave) * 8192 + lane * 16;

    auto issue = [&](int kb, int buf) {
        #pragma unroll
        for (int pp = 0; pp < 2; ++pp) {
            async16(srcA + pp * 8192 + kb * 1024,
                    &LDS[buf][(2 * wave + pp) * 1024]);
            async16(srcB + pp * 8192 + kb * 1024,
                    &LDS[buf][8192 + (2 * wave + pp) * 1024]);
        }
    };

    issue(0, 0);

    #pragma unroll 1
    for (int kb = 0; kb < 8; ++kb) {
        const int buf = kb & 1;
        // drain this buf's DMAs; barrier also fences prev iter's reads of buf^1
        __builtin_amdgcn_s_waitcnt(0xF70);   // vmcnt(0)
        __syncthreads();
        if (kb < 7) issue(kb + 1, buf ^ 1);  // prefetch flies during compute

        #pragma unroll
        for (int ss = 0; ss < 2; ++ss) {     // two K=64 sub-steps per 128-k stage
            const int s    = ss * 2 + h;     // 32-k slot index 0..3
            const int slot = ((s ^ (rp & 3) ^ pa) << 4);
            i32x8_t af[2], bf[2];
            #pragma unroll
            for (int mt = 0; mt < 2; ++mt) {
                const i32x4_t v = *reinterpret_cast<const i32x4_t*>(
                    &LDS[buf][((wRow >> 4) + mt * 2 + pa) * 1024 + rp * 64 + slot]);
                af[mt][0] = v[0]; af[mt][1] = v[1]; af[mt][2] = v[2]; af[mt][3] = v[3];
                af[mt][4] = 0;    af[mt][5] = 0;    af[mt][6] = 0;    af[mt][7] = 0;
            }
            #pragma unroll
            for (int nt = 0; nt < 2; ++nt) {
                const i32x4_t v = *reinterpret_cast<const i32x4_t*>(
                    &LDS[buf][8192 + ((wCol >> 4) + nt * 2 + pa) * 1024 + rp * 64 + slot]);
                bf[nt][0] = v[0]; bf[nt][1] = v[1]; bf[nt][2] = v[2]; bf[nt][3] = v[3];
                bf[nt][4] = 0;    bf[nt][5] = 0;    bf[nt][6] = 0;    bf[nt][7] = 0;
            }
            #pragma unroll
            for (int mt = 0; mt < 2; ++mt)
                #pragma unroll
                for (int nt = 0; nt < 2; ++nt)
                    acc[mt][nt] = __builtin_amdgcn_mfma_scale_f32_32x32x64_f8f6f4(
                        af[mt], bf[nt], acc[mt][nt],
                        4, 4,                       // cbsz=fp4(e2m1), blgp=fp4(e2m1)
                        0, 0x7F7F7F7F,              // A scales: E8M0 127 = 2^0
                        0, 0x7F7F7F7F);             // B scales: 2^0
        }
    }

    // Epilogue (r5-exact): acc holds 1024*S -> E = exp2(acc/(1024*TAU*ln2)).
    const float kScale = (float)(1.0 / (1024.0 * 0.07 * 0.6931471805599453));
    float cs[2] = {0.f, 0.f};
    #pragma unroll
    for (int mt = 0; mt < 2; ++mt) {
        float rs[16];
        #pragma unroll
        for (int reg = 0; reg < 16; ++reg) rs[reg] = 0.f;
        #pragma unroll
        for (int nt = 0; nt < 2; ++nt)
            #pragma unroll
            for (int reg = 0; reg < 16; ++reg) {
                const float e = exp2f(acc[mt][nt][reg] * kScale);
                rs[reg] += e;
                cs[nt]  += e;
            }
        // reduce each row over the 32 cols held in this lane-half
        #pragma unroll
        for (int reg = 0; reg < 16; ++reg) {
            float v = rs[reg];
            v += __shfl_xor(v, 1, 64);
            v += __shfl_xor(v, 2, 64);
            v += __shfl_xor(v, 4, 64);
            v += __shfl_xor(v, 8, 64);
            v += __shfl_xor(v, 16, 64);
            if (r32 == 0)   // lanes 0 and 32: rows of their half
                atomicAdd(&rowsum[R0 + wRow + mt * 32
                                  + (reg & 3) + 8 * (reg >> 2) + 4 * h], v);
        }
    }
    #pragma unroll
    for (int nt = 0; nt < 2; ++nt) {
        float v = cs[nt];
        v += __shfl_xor(v, 32, 64);          // combine halves (same col)
        if (h == 0)
            atomicAdd(&colsum[C0 + wCol + nt * 32 + r32], v);
    }
}

// ---------------------------------------------------------------------------
// Kernel 3 (r10): 16-block parallel finalize (r7 pattern, reading the final
// rowsum/colsum directly). 16-block done-counter convoy is negligible.
// ---------------------------------------------------------------------------
__global__ __launch_bounds__(256) void finalize(
    const float* __restrict__ rowsum, const float* __restrict__ colsum,
    const float* __restrict__ sdiag, double* __restrict__ accum,
    unsigned* __restrict__ donecnt, float* __restrict__ out)
{
    const int t = threadIdx.x;
    const int i = blockIdx.x * 256 + t;

    const float extra = (float)(NB * 1e-6 + 1e-6);
    double local = (double)sdiag[i] * (2.0 / 0.07)
                 - (double)logf(rowsum[i] + extra)
                 - (double)logf(colsum[i] + extra);

    #pragma unroll
    for (int off = 1; off < 64; off <<= 1)
        local += __shfl_xor(local, off, 64);
    __shared__ double dred[4];
    __shared__ unsigned lastFlag;
    if ((t & 63) == 0) dred[t >> 6] = local;
    __syncthreads();
    if (t == 0) {
        double bsum = dred[0] + dred[1] + dred[2] + dred[3];
        atomicAdd(accum, bsum);
        __threadfence();
        const unsigned old = __hip_atomic_fetch_add(
            donecnt, 1u, __ATOMIC_ACQ_REL, __HIP_MEMORY_SCOPE_AGENT);
        lastFlag = (old == 15u) ? 1u : 0u;
    }
    __syncthreads();
    if (lastFlag && t == 0) {
        const double a = __hip_atomic_load(accum, __ATOMIC_RELAXED,
                                           __HIP_MEMORY_SCOPE_AGENT);
        out[0] = (float)(a * (-1.0 / (2.0 * NB)));
    }
}

// ---------------------------------------------------------------------------
extern "C" void kernel_launch(void* const* d_in, const int* in_sizes, int n_in,
                              void* d_out, int out_size, void* d_ws, size_t ws_size,
                              hipStream_t stream)
{
    const float* x = (const float*)d_in[0];
    const float* y = (const float*)d_in[1];
    float* out = (float*)d_out;

    char* ws = (char*)d_ws;
    unsigned char* xq = (unsigned char*)ws;                                 // 2 MB fp4 swizzled
    unsigned char* yq = (unsigned char*)(ws + (size_t)2 * 1024 * 1024);     // 2 MB fp4 swizzled
    float* rowsum = (float*)(ws + (size_t)8 * 1024 * 1024);                 // 16 KB
    float* colsum = rowsum + NB;                                            // 16 KB
    float* sdiag  = colsum + NB;                                            // 16 KB
    double* accum = (double*)(sdiag + NB);                                  // 8 B
    unsigned* donecnt = (unsigned*)(accum + 1);                             // 4 B

    normalize_rows<<<NB / 4, 256, 0, stream>>>(x, y, xq, yq, sdiag,
                                               rowsum, accum, donecnt);

    dim3 grid(32, 32);   // 128x128 tiles, 1024 blocks = 4/CU
    gemm_exp_sums<<<grid, 256, 0, stream>>>(xq, yq, rowsum, colsum);

    finalize<<<16, 256, 0, stream>>>(rowsum, colsum, sdiag,
                                     accum, donecnt, out);
}

// Round 11
// 95.819 us; speedup vs baseline: 2.8733x; 1.1304x over previous
//
#include <hip/hip_runtime.h>

#define NB 4096
#define DK 1024
#define EPSF 1e-6f
#define QS 32.0f          // fp4 pre-scale 2^5: normalized entries sigma=1/32 -> sigma=1

typedef __attribute__((ext_vector_type(8))) int   i32x8_t;
typedef __attribute__((ext_vector_type(4))) int   i32x4_t;
typedef __attribute__((ext_vector_type(4))) float f32x4_t;

#if defined(__has_builtin)
#if __has_builtin(__builtin_amdgcn_cvt_scalef32_pk_fp4_f32)
#define HW_FP4 1
#endif
#endif

// ---------------------------------------------------------------------------
// Global fp4 layout (r11: 3-term swizzle): row,k -> p=row>>4, r=row&15,
// kb=k>>7, slot s=(k>>5)&3:
//   byte = p*8192 + kb*1024 + r*64 + ((s ^ (r&3) ^ (r>>2))<<4) + ((k&31)>>1)
// (p,kb) chunk = 1 KB contiguous -> one 64-lane x 16 B DMA (linear LDS dest,
// pre-swizzled source; fragment read applies the same XOR -> rule #21 ok).
// vs r4's 2-term (s^(r&3)): the added ^(r>>2) spreads lanes {0,4,8,12} of a
// fragment read across 4 distinct 16-B bank slots -> LDS read conflict drops
// 4-way (1.58x cost, m136) to 2-way (free). Bank check: conflict iff same
// (r&1, slot); slot = q^(r&3)^(r>>2) gives only {0,10},{2,8},{4,14},{6,12}
// 2-way pairs among same-parity rows.
// ---------------------------------------------------------------------------

__device__ __forceinline__ void async16(const void* g, void* lds) {
    __builtin_amdgcn_global_load_lds(
        (const __attribute__((address_space(1))) void*)g,
        (__attribute__((address_space(3))) void*)lds, 16, 0, 0);
}

// branchless e2m1 encode fallback: grid 0,.5,1,1.5,2,3,4,6.
__device__ __forceinline__ unsigned enc4(float v) {
    const float a = fabsf(v);
    unsigned c = (a >= 0.25f) + (a >= 0.75f) + (a >= 1.25f) + (a >= 1.75f)
               + (a >= 2.5f)  + (a >= 3.5f)  + (a >= 5.0f);
    return c | ((v < 0.f) ? 8u : 0u);
}

// ---------------------------------------------------------------------------
// Kernel 1 (r4 body + r11 swizzle): wave-per-row normalize -> fp4 e2m1
// swizzled; exact fp32 diagonal; zeroes rowsum/colsum.
// ---------------------------------------------------------------------------
__global__ __launch_bounds__(256) void normalize_rows(
    const float* __restrict__ x, const float* __restrict__ y,
    unsigned char* __restrict__ xq, unsigned char* __restrict__ yq,
    float* __restrict__ sdiag, float* __restrict__ zerobuf)
{
    const int t = threadIdx.x;
    const int gid = blockIdx.x * 256 + t;
    if (gid < 2 * NB) zerobuf[gid] = 0.f;   // rowsum+colsum contiguous

    const int wave = t >> 6;
    const int lane = t & 63;
    const int row  = blockIdx.x * 4 + wave;

    const float4* xr = reinterpret_cast<const float4*>(x + (size_t)row * DK);
    const float4* yr = reinterpret_cast<const float4*>(y + (size_t)row * DK);

    float4 xv[4], yv[4];
    float ssx = 0.f, ssy = 0.f, sxy = 0.f;
    #pragma unroll
    for (int jj = 0; jj < 4; ++jj) {
        xv[jj] = xr[lane * 4 + jj];
        yv[jj] = yr[lane * 4 + jj];
        ssx += xv[jj].x*xv[jj].x + xv[jj].y*xv[jj].y + xv[jj].z*xv[jj].z + xv[jj].w*xv[jj].w;
        ssy += yv[jj].x*yv[jj].x + yv[jj].y*yv[jj].y + yv[jj].z*yv[jj].z + yv[jj].w*yv[jj].w;
        sxy += xv[jj].x*yv[jj].x + xv[jj].y*yv[jj].y + xv[jj].z*yv[jj].z + xv[jj].w*yv[jj].w;
    }
    #pragma unroll
    for (int off = 1; off < 64; off <<= 1) {
        ssx += __shfl_xor(ssx, off, 64);
        ssy += __shfl_xor(ssy, off, 64);
        sxy += __shfl_xor(sxy, off, 64);
    }
    const float invx = 1.0f / fmaxf(sqrtf(ssx), EPSF);
    const float invy = 1.0f / fmaxf(sqrtf(ssy), EPSF);
    const float sx = invx * QS;
    const float sy = invy * QS;

    float fx[16], fy[16];
    #pragma unroll
    for (int jj = 0; jj < 4; ++jj) {
        fx[jj*4+0] = xv[jj].x; fx[jj*4+1] = xv[jj].y;
        fx[jj*4+2] = xv[jj].z; fx[jj*4+3] = xv[jj].w;
        fy[jj*4+0] = yv[jj].x; fy[jj*4+1] = yv[jj].y;
        fy[jj*4+2] = yv[jj].z; fy[jj*4+3] = yv[jj].w;
    }

    unsigned xb0, xb1, yb0, yb1;
#ifdef HW_FP4
    // byte m = {fp4(f[2m+1])<<4 | fp4(f[2m])}: pk convention src0 -> low nibble.
    #define CVT8(dst, f, s)                                                        \
        dst = __builtin_amdgcn_cvt_scalef32_pk_fp4_f32(0u,  (f)[0]*(s), (f)[1]*(s), 1.0f, 0); \
        dst = __builtin_amdgcn_cvt_scalef32_pk_fp4_f32(dst, (f)[2]*(s), (f)[3]*(s), 1.0f, 1); \
        dst = __builtin_amdgcn_cvt_scalef32_pk_fp4_f32(dst, (f)[4]*(s), (f)[5]*(s), 1.0f, 2); \
        dst = __builtin_amdgcn_cvt_scalef32_pk_fp4_f32(dst, (f)[6]*(s), (f)[7]*(s), 1.0f, 3)
    CVT8(xb0, fx,     sx);
    CVT8(xb1, fx + 8, sx);
    CVT8(yb0, fy,     sy);
    CVT8(yb1, fy + 8, sy);
    #undef CVT8
#else
    unsigned xb[2] = {0u, 0u}, yb[2] = {0u, 0u};
    #pragma unroll
    for (int j = 0; j < 16; ++j) {
        xb[j >> 3] |= enc4(fx[j] * sx) << ((j & 7) * 4);
        yb[j >> 3] |= enc4(fy[j] * sy) << ((j & 7) * 4);
    }
    xb0 = xb[0]; xb1 = xb[1]; yb0 = yb[0]; yb1 = yb[1];
#endif

    // lane owns k[16*lane,16*lane+16): kb=lane>>3, s=(lane&7)>>1, lo8=(lane&1)*8
    const int p = row >> 4, r = row & 15;
    const unsigned off = (unsigned)p * 8192 + (lane >> 3) * 1024 + r * 64
                       + ((((lane & 7) >> 1) ^ (r & 3) ^ (r >> 2)) << 4)
                       + (lane & 1) * 8;
    *reinterpret_cast<uint2*>(xq + off) = make_uint2(xb0, xb1);
    *reinterpret_cast<uint2*>(yq + off) = make_uint2(yb0, yb1);

    if (lane == 0) sdiag[row] = sxy * invx * invy;
}

// ---------------------------------------------------------------------------
// Kernel 2 (r11 = r4-exact + 3-term swizzle): m97 structure, 128x128 tile,
// 4 waves, 4 blocks/CU (all 1024 blocks resident in one round), dbuf
// global_load_lds, one drain+barrier per K-step, 16x16x128 fp4 core.
// r4 measured 95.6 total (session best); only delta here is the fragment
// read slot sl gaining ^(l15>>2) to match the layout (4-way -> 2-way LDS
// bank degree on every A/B fragment ds_read_b128).
// ---------------------------------------------------------------------------
__global__ __launch_bounds__(256, 4) void gemm_exp_sums(
    const unsigned char* __restrict__ xq, const unsigned char* __restrict__ yq,
    float* __restrict__ rowsum, float* __restrict__ colsum)
{
    __shared__ __align__(16) unsigned char LDS[2][16384];  // [buf][A:0-8K | B:8K-16K]

    const int t    = threadIdx.x;
    const int lane = t & 63;
    const int wave = t >> 6;        // 0..3
    const int q    = lane >> 4;
    const int l15  = lane & 15;

    const int R0 = blockIdx.y * 128;
    const int C0 = blockIdx.x * 128;
    const int wRow = (wave >> 1) * 64;   // 0 or 64
    const int wCol = (wave & 1) * 64;    // 0 or 64

    f32x4_t acc[4][4];
    #pragma unroll
    for (int i = 0; i < 4; i++)
        #pragma unroll
        for (int j = 0; j < 4; j++)
            acc[i][j] = (f32x4_t){0.f, 0.f, 0.f, 0.f};

    // wave w stages A panels {2w,2w+1} and B panels {2w,2w+1}: 4 DMAs/lane/stage
    const unsigned char* srcA =
        xq + (size_t)((R0 >> 4) + 2 * wave) * 8192 + lane * 16;
    const unsigned char* srcB =
        yq + (size_t)((C0 >> 4) + 2 * wave) * 8192 + lane * 16;

    auto issue = [&](int kb, int buf) {
        #pragma unroll
        for (int pp = 0; pp < 2; ++pp) {
            async16(srcA + pp * 8192 + kb * 1024,
                    &LDS[buf][(2 * wave + pp) * 1024]);
            async16(srcB + pp * 8192 + kb * 1024,
                    &LDS[buf][8192 + (2 * wave + pp) * 1024]);
        }
    };

    issue(0, 0);

    // fragment read: row l15, logical k-slot q -> physical slot q^(l15&3)^(l15>>2)
    const int sl = ((q ^ (l15 & 3) ^ (l15 >> 2)) << 4);

    #pragma unroll 1
    for (int kb = 0; kb < 8; ++kb) {
        const int buf = kb & 1;
        // drain this buf's DMAs; barrier also fences prev iter's reads of buf^1
        __builtin_amdgcn_s_waitcnt(0xF70);   // vmcnt(0), lgkm/exp no-wait
        __syncthreads();
        if (kb < 7) issue(kb + 1, buf ^ 1);  // prefetch flies during compute

        i32x8_t bfr[4];
        #pragma unroll
        for (int nt = 0; nt < 4; ++nt) {
            const i32x4_t v = *reinterpret_cast<const i32x4_t*>(
                &LDS[buf][8192 + ((wCol >> 4) + nt) * 1024 + l15 * 64 + sl]);
            bfr[nt][0] = v[0]; bfr[nt][1] = v[1]; bfr[nt][2] = v[2]; bfr[nt][3] = v[3];
            bfr[nt][4] = 0;    bfr[nt][5] = 0;    bfr[nt][6] = 0;    bfr[nt][7] = 0;
        }
        #pragma unroll
        for (int mt = 0; mt < 4; ++mt) {
            const i32x4_t v = *reinterpret_cast<const i32x4_t*>(
                &LDS[buf][((wRow >> 4) + mt) * 1024 + l15 * 64 + sl]);
            i32x8_t af;
            af[0] = v[0]; af[1] = v[1]; af[2] = v[2]; af[3] = v[3];
            af[4] = 0;    af[5] = 0;    af[6] = 0;    af[7] = 0;
            #pragma unroll
            for (int nt = 0; nt < 4; ++nt)
                acc[mt][nt] = __builtin_amdgcn_mfma_scale_f32_16x16x128_f8f6f4(
                    af, bfr[nt], acc[mt][nt],
                    4, 4,                       // cbsz=fp4(e2m1), blgp=fp4(e2m1)
                    0, 0x7F7F7F7F,              // A scales: E8M0 127 = 2^0
                    0, 0x7F7F7F7F);             // B scales: 2^0
        }
    }

    // Epilogue: acc holds 1024*S (32x32 pre-scale) -> E = exp2(acc/(1024*TAU*ln2)).
    const float kScale = (float)(1.0 / (1024.0 * 0.07 * 0.6931471805599453));
    float csum[4] = {0.f, 0.f, 0.f, 0.f};
    #pragma unroll
    for (int mt = 0; mt < 4; ++mt) {
        float rsum[4] = {0.f, 0.f, 0.f, 0.f};
        #pragma unroll
        for (int nt = 0; nt < 4; ++nt) {
            #pragma unroll
            for (int r = 0; r < 4; ++r) {
                const float e = exp2f(acc[mt][nt][r] * kScale);
                rsum[r]  += e;
                csum[nt] += e;
            }
        }
        #pragma unroll
        for (int r = 0; r < 4; ++r) {
            float v = rsum[r];
            v += __shfl_xor(v, 1, 64);
            v += __shfl_xor(v, 2, 64);
            v += __shfl_xor(v, 4, 64);
            v += __shfl_xor(v, 8, 64);
            if (l15 == 0)
                atomicAdd(&rowsum[R0 + wRow + mt * 16 + q * 4 + r], v);
        }
    }
    #pragma unroll
    for (int nt = 0; nt < 4; ++nt) {
        float v = csum[nt];
        v += __shfl_xor(v, 16, 64);
        v += __shfl_xor(v, 32, 64);
        if (lane < 16)
            atomicAdd(&colsum[C0 + wCol + nt * 16 + l15], v);
    }
}

// ---------------------------------------------------------------------------
// Kernel 3 (r4-exact): loss = -1/(2B) [ (2/TAU)*sum(sdiag)
//                      - sum(log(rowsum+extra)) - sum(log(colsum+extra)) ]
// ---------------------------------------------------------------------------
__global__ __launch_bounds__(1024) void finalize(
    const float* __restrict__ rowsum, const float* __restrict__ colsum,
    const float* __restrict__ sdiag, float* __restrict__ out)
{
    const float extra = (float)(NB * 1e-6 + 1e-6);
    double local = 0.0;
    for (int i = threadIdx.x; i < NB; i += 1024) {
        local += (double)sdiag[i] * (2.0 / 0.07)
               - (double)logf(rowsum[i] + extra)
               - (double)logf(colsum[i] + extra);
    }
    #pragma unroll
    for (int off = 1; off < 64; off <<= 1)
        local += __shfl_xor(local, off, 64);
    __shared__ double dred[16];
    const int wave = threadIdx.x >> 6;
    if ((threadIdx.x & 63) == 0) dred[wave] = local;
    __syncthreads();
    if (threadIdx.x == 0) {
        double tot = 0.0;
        #pragma unroll
        for (int w = 0; w < 16; ++w) tot += dred[w];
        out[0] = (float)(tot * (-1.0 / (2.0 * NB)));
    }
}

// ---------------------------------------------------------------------------
extern "C" void kernel_launch(void* const* d_in, const int* in_sizes, int n_in,
                              void* d_out, int out_size, void* d_ws, size_t ws_size,
                              hipStream_t stream)
{
    const float* x = (const float*)d_in[0];
    const float* y = (const float*)d_in[1];
    float* out = (float*)d_out;

    char* ws = (char*)d_ws;
    unsigned char* xq = (unsigned char*)ws;                                 // 2 MB fp4 swizzled
    unsigned char* yq = (unsigned char*)(ws + (size_t)2 * 1024 * 1024);     // 2 MB fp4 swizzled
    float* rowsum = (float*)(ws + (size_t)8 * 1024 * 1024);                 // 16 KB
    float* colsum = rowsum + NB;                                            // 16 KB
    float* sdiag  = colsum + NB;                                            // 16 KB

    normalize_rows<<<NB / 4, 256, 0, stream>>>(x, y, xq, yq, sdiag, rowsum);

    dim3 grid(32, 32);   // 128x128 tiles, 1024 blocks = 4/CU
    gemm_exp_sums<<<grid, 256, 0, stream>>>(xq, yq, rowsum, colsum);

    finalize<<<1, 1024, 0, stream>>>(rowsum, colsum, sdiag, out);
}